// Round 1
// baseline (240.677 us; speedup 1.0000x reference)
//
#include <hip/hip_runtime.h>
#include <cstdint>
#include <cstddef>

// Problem constants
#define SEQ 2048
#define HID 1024
#define NHEAD 16
#define HDIM 64

typedef _Float16 f16;
typedef f16 half8 __attribute__((ext_vector_type(8)));
typedef f16 half4 __attribute__((ext_vector_type(4)));
typedef float f32x4 __attribute__((ext_vector_type(4)));

// async global->LDS, 16B per lane. LDS dest must be wave-uniform base; HW
// writes base + lane*16 (m104/m108). Global addr is per-lane.
#define ASYNC_COPY16(g, l)                                                    \
  __builtin_amdgcn_global_load_lds(                                           \
      (const __attribute__((address_space(1))) void*)(const void*)(g),        \
      (__attribute__((address_space(3))) void*)(void*)(l), 16, 0, 0)

// ---------------------------------------------------------------------------
// fp32 -> f16 cast (4 elements / thread)
__global__ void cast_f32_f16(const float* __restrict__ src,
                             f16* __restrict__ dst, int n) {
  int i = (blockIdx.x * blockDim.x + threadIdx.x) * 4;
  if (i < n) {
    float4 v = *(const float4*)(src + i);
    half4 h;
    h[0] = (f16)v.x; h[1] = (f16)v.y; h[2] = (f16)v.z; h[3] = (f16)v.w;
    *(half4*)(dst + i) = h;
  }
}

// ---------------------------------------------------------------------------
// src[R][C] fp32 -> dst[C][R] f16 (LDS-tiled transpose, both sides coalesced)
__global__ void transpose_cast(const float* __restrict__ src,
                               f16* __restrict__ dst, int R, int C) {
  __shared__ float tile[32][33];
  int c0 = blockIdx.x * 32, r0 = blockIdx.y * 32;
  int tx = threadIdx.x, ty = threadIdx.y;  // 32 x 8
#pragma unroll
  for (int i = 0; i < 32; i += 8)
    tile[ty + i][tx] = src[(size_t)(r0 + ty + i) * C + c0 + tx];
  __syncthreads();
#pragma unroll
  for (int i = 0; i < 32; i += 8)
    dst[(size_t)(c0 + ty + i) * R + r0 + tx] = (f16)tile[tx][ty + i];
}

// ---------------------------------------------------------------------------
// C = A[M,K] * Bt[N,K]^T + bias ; 128x128 tile, BK=32, 4 waves (2x2 of 64x64)
// m97 structure: global_load_lds dwordx4 staging, ds_read_b128 fragments.
template <bool OUT16>
__global__ __launch_bounds__(256) void gemm_f16(
    const f16* __restrict__ A, const f16* __restrict__ Bt,
    const float* __restrict__ bias, void* __restrict__ Cout, int M, int N,
    int K) {
  __shared__ __align__(16) f16 sA[128 * 32];
  __shared__ __align__(16) f16 sB[128 * 32];
  const int tid = threadIdx.x;
  const int wave = tid >> 6, lane = tid & 63;
  const int quad = lane >> 4, l16 = lane & 15;
  const int m0 = blockIdx.y * 128, n0 = blockIdx.x * 128;
  const int wm = (wave >> 1) * 64, wn = (wave & 1) * 64;
  const int rowA = lane >> 2, chunkA = lane & 3;  // 4 rows of 64B per 16 lanes

  f32x4 acc[4][4] = {};

  for (int k0 = 0; k0 < K; k0 += 32) {
#pragma unroll
    for (int i = 0; i < 2; i++) {
      int r = wave * 2 + i;  // region: 16 rows x 32 f16 = 1KB
      const f16* ga = A + (size_t)(m0 + r * 16 + rowA) * K + k0 + chunkA * 8;
      ASYNC_COPY16(ga, &sA[r * 512]);
      const f16* gb = Bt + (size_t)(n0 + r * 16 + rowA) * K + k0 + chunkA * 8;
      ASYNC_COPY16(gb, &sB[r * 512]);
    }
    __syncthreads();  // drains vmcnt (compiler emits vmcnt(0) before barrier)

    half8 af[4], bf[4];
#pragma unroll
    for (int i = 0; i < 4; i++) {
      af[i] = *(const half8*)&sA[(wm + i * 16 + l16) * 32 + quad * 8];
      bf[i] = *(const half8*)&sB[(wn + i * 16 + l16) * 32 + quad * 8];
    }
#pragma unroll
    for (int i = 0; i < 4; i++)
#pragma unroll
      for (int j = 0; j < 4; j++)
        acc[i][j] = __builtin_amdgcn_mfma_f32_16x16x32_f16(af[i], bf[j],
                                                           acc[i][j], 0, 0, 0);
    __syncthreads();
  }

  // epilogue: C/D layout row=(quad*4+r), col=l16 (verified m89/m91)
#pragma unroll
  for (int i = 0; i < 4; i++) {
    int row = m0 + wm + i * 16 + quad * 4;
#pragma unroll
    for (int j = 0; j < 4; j++) {
      int col = n0 + wn + j * 16 + l16;
      float bv = bias[col];
#pragma unroll
      for (int r = 0; r < 4; r++) {
        float v = acc[i][j][r] + bv;
        if (OUT16)
          ((f16*)Cout)[(size_t)(row + r) * N + col] = (f16)v;
        else
          ((float*)Cout)[(size_t)(row + r) * N + col] = v;
      }
    }
  }
}

// ---------------------------------------------------------------------------
// Fused causal flash attention. qkv: [SEQ][3*HID] f16 (Q|K|V concatenated).
// Grid: (SEQ/64, NHEAD). Block: 256 (4 waves, each owns 16 q-rows).
__global__ __launch_bounds__(256) void attn_fused(const f16* __restrict__ qkv,
                                                  f16* __restrict__ out) {
  const int h = blockIdx.y;
  const int q0 = blockIdx.x * 64;
  __shared__ __align__(16) f16 sK[64 * 64];       // [s_k][d]
  __shared__ __align__(16) f16 sVt[64 * 64];      // [d][s_k]
  __shared__ __align__(16) f16 sP[4][16 * 64];    // per-wave P scratch
  const int tid = threadIdx.x;
  const int wave = tid >> 6, lane = tid & 63;
  const int quad = lane >> 4, l16 = lane & 15;

  // Q A-fragments: A[m=l16][k=quad*8+j] (+32 for second k-step); kept in regs
  const f16* qbase =
      qkv + (size_t)(q0 + wave * 16 + l16) * 3072 + h * HDIM + quad * 8;
  const half8 qf0 = *(const half8*)qbase;
  const half8 qf1 = *(const half8*)(qbase + 32);

  f32x4 o[4] = {};
  float m_i[4], l_i[4];
#pragma unroll
  for (int r = 0; r < 4; r++) {
    m_i[r] = -1e30f;
    l_i[r] = 0.f;
  }

  const int nkt = q0 / 64 + 1;  // causal: only tiles with k0 <= q0
  for (int kt = 0; kt < nkt; kt++) {
    const int k0 = kt * 64;
    // stage K tile [64][64] via async copy (8 regions of 8 rows x 128B)
#pragma unroll
    for (int i = 0; i < 2; i++) {
      int r = wave * 2 + i;
      const f16* gk = qkv + (size_t)(k0 + r * 8 + (lane >> 3)) * 3072 + HID +
                      h * HDIM + (lane & 7) * 8;
      ASYNC_COPY16(gk, &sK[r * 512]);
    }
    // stage V transposed: coalesced 16B global loads, scalar LDS scatter
#pragma unroll
    for (int c = tid; c < 512; c += 256) {
      int s = c >> 3, d0 = (c & 7) * 8;
      half8 v =
          *(const half8*)(qkv + (size_t)(k0 + s) * 3072 + 2 * HID + h * HDIM + d0);
#pragma unroll
      for (int j = 0; j < 8; j++) sVt[(d0 + j) * 64 + s] = v[j];
    }
    __syncthreads();

    // S = Q K^T : B-frag B[k=d][n=s_k] = sK[s_k][d], contiguous reads
    f32x4 sacc[4] = {};
#pragma unroll
    for (int n = 0; n < 4; n++) {
      half8 kf0 = *(const half8*)&sK[(n * 16 + l16) * 64 + quad * 8];
      half8 kf1 = *(const half8*)&sK[(n * 16 + l16) * 64 + 32 + quad * 8];
      sacc[n] = __builtin_amdgcn_mfma_f32_16x16x32_f16(qf0, kf0, sacc[n], 0, 0, 0);
      sacc[n] = __builtin_amdgcn_mfma_f32_16x16x32_f16(qf1, kf1, sacc[n], 0, 0, 0);
    }
    // scale + causal mask (C layout: row=quad*4+r, col=n*16+l16)
    const int rowg_base = q0 + wave * 16 + quad * 4;
#pragma unroll
    for (int n = 0; n < 4; n++) {
      int colg = k0 + n * 16 + l16;
#pragma unroll
      for (int r = 0; r < 4; r++) {
        float v = sacc[n][r] * 0.125f;
        if (colg > rowg_base + r) v = -1e30f;
        sacc[n][r] = v;
      }
    }
    // online softmax (reduce across the 16 lanes of each quad = one row)
#pragma unroll
    for (int r = 0; r < 4; r++) {
      float mx = fmaxf(fmaxf(sacc[0][r], sacc[1][r]),
                       fmaxf(sacc[2][r], sacc[3][r]));
#pragma unroll
      for (int off = 1; off < 16; off <<= 1) mx = fmaxf(mx, __shfl_xor(mx, off));
      float mnew = fmaxf(m_i[r], mx);
      float alpha = __expf(m_i[r] - mnew);
      float rs = 0.f;
#pragma unroll
      for (int n = 0; n < 4; n++) {
        float p = __expf(sacc[n][r] - mnew);
        sacc[n][r] = p;
        rs += p;
      }
#pragma unroll
      for (int off = 1; off < 16; off <<= 1) rs += __shfl_xor(rs, off);
      l_i[r] = l_i[r] * alpha + rs;
      m_i[r] = mnew;
#pragma unroll
      for (int j = 0; j < 4; j++) o[j][r] *= alpha;
    }
    // P: C-layout -> LDS -> A-layout (within-wave round trip, no barrier
    // needed: wave-private region, LDS ops in-order within a wave)
#pragma unroll
    for (int n = 0; n < 4; n++)
#pragma unroll
      for (int r = 0; r < 4; r++)
        sP[wave][(quad * 4 + r) * 64 + n * 16 + l16] = (f16)sacc[n][r];
    half8 pf0 = *(const half8*)&sP[wave][l16 * 64 + quad * 8];
    half8 pf1 = *(const half8*)&sP[wave][l16 * 64 + 32 + quad * 8];
    // O += P V : B-frag B[k=s_k][n=d] = sVt[d][s_k], contiguous reads
#pragma unroll
    for (int j = 0; j < 4; j++) {
      half8 vf0 = *(const half8*)&sVt[(j * 16 + l16) * 64 + quad * 8];
      half8 vf1 = *(const half8*)&sVt[(j * 16 + l16) * 64 + 32 + quad * 8];
      o[j] = __builtin_amdgcn_mfma_f32_16x16x32_f16(pf0, vf0, o[j], 0, 0, 0);
      o[j] = __builtin_amdgcn_mfma_f32_16x16x32_f16(pf1, vf1, o[j], 0, 0, 0);
    }
    __syncthreads();  // protect sK/sVt before next tile's staging
  }

  // epilogue: out[q][h*64+d] f16
#pragma unroll
  for (int j = 0; j < 4; j++) {
    int col = h * HDIM + j * 16 + l16;
#pragma unroll
    for (int r = 0; r < 4; r++) {
      int row = q0 + wave * 16 + quad * 4 + r;
      out[(size_t)row * HID + col] = (f16)(o[j][r] / l_i[r]);
    }
  }
}

// ---------------------------------------------------------------------------
extern "C" void kernel_launch(void* const* d_in, const int* in_sizes, int n_in,
                              void* d_out, int out_size, void* d_ws,
                              size_t ws_size, hipStream_t stream) {
  const float* h = (const float*)d_in[0];    // [2048,1024]
  const float* wa = (const float*)d_in[1];   // [1024,3072]
  const float* ba = (const float*)d_in[2];   // [3072]
  const float* wp = (const float*)d_in[3];   // [1024,1024]
  const float* bp = (const float*)d_in[4];   // [1024]
  float* out = (float*)d_out;                // [2048,1024] fp32

  char* ws = (char*)d_ws;
  f16* h16 = (f16*)(ws);                       //  4 MiB
  f16* waT = (f16*)(ws + (4u << 20));          //  6 MiB  [3072][1024]
  f16* wpT = (f16*)(ws + (10u << 20));         //  2 MiB  [1024][1024]
  f16* qkv = (f16*)(ws + (12u << 20));         // 12 MiB  [2048][3072]
  f16* attn = (f16*)(ws + (24u << 20));        //  4 MiB  [2048][1024]

  cast_f32_f16<<<2048, 256, 0, stream>>>(h, h16, SEQ * HID);
  transpose_cast<<<dim3(96, 32), dim3(32, 8), 0, stream>>>(wa, waT, 1024, 3072);
  transpose_cast<<<dim3(32, 32), dim3(32, 8), 0, stream>>>(wp, wpT, 1024, 1024);
  // QKV = H @ Wattn + b  -> f16
  gemm_f16<true><<<dim3(24, 16), 256, 0, stream>>>(h16, waT, ba, qkv, SEQ,
                                                   3 * HID, HID);
  // fused causal attention
  attn_fused<<<dim3(SEQ / 64, NHEAD), 256, 0, stream>>>(qkv, attn);
  // OUT = attn @ Wproj + b -> fp32
  gemm_f16<false><<<dim3(8, 16), 256, 0, stream>>>(attn, wpT, bp, out, SEQ,
                                                   HID, HID);
}

// Round 2
// 199.362 us; speedup vs baseline: 1.2072x; 1.2072x over previous
//
#include <hip/hip_runtime.h>
#include <cstdint>
#include <cstddef>

// Problem constants
#define SEQ 2048
#define HID 1024
#define NHEAD 16
#define HDIM 64

typedef _Float16 f16;
typedef f16 half8 __attribute__((ext_vector_type(8)));
typedef f16 half4 __attribute__((ext_vector_type(4)));
typedef float f32x4 __attribute__((ext_vector_type(4)));

// async global->LDS, 16B per lane. LDS dest must be wave-uniform base; HW
// writes base + lane*16 (m104/m108). Global addr is per-lane.
#define ASYNC_COPY16(g, l)                                                    \
  __builtin_amdgcn_global_load_lds(                                           \
      (const __attribute__((address_space(1))) void*)(const void*)(g),        \
      (__attribute__((address_space(3))) void*)(void*)(l), 16, 0, 0)

// ---------------------------------------------------------------------------
// fp32 -> f16 cast (4 elements / thread)
__global__ void cast_f32_f16(const float* __restrict__ src,
                             f16* __restrict__ dst, int n) {
  int i = (blockIdx.x * blockDim.x + threadIdx.x) * 4;
  if (i < n) {
    float4 v = *(const float4*)(src + i);
    half4 h;
    h[0] = (f16)v.x; h[1] = (f16)v.y; h[2] = (f16)v.z; h[3] = (f16)v.w;
    *(half4*)(dst + i) = h;
  }
}

// ---------------------------------------------------------------------------
// src[R][C] fp32 -> dst[C][R] f16 (LDS-tiled transpose, both sides coalesced)
__global__ void transpose_cast(const float* __restrict__ src,
                               f16* __restrict__ dst, int R, int C) {
  __shared__ float tile[32][33];
  int c0 = blockIdx.x * 32, r0 = blockIdx.y * 32;
  int tx = threadIdx.x, ty = threadIdx.y;  // 32 x 8
#pragma unroll
  for (int i = 0; i < 32; i += 8)
    tile[ty + i][tx] = src[(size_t)(r0 + ty + i) * C + c0 + tx];
  __syncthreads();
#pragma unroll
  for (int i = 0; i < 32; i += 8)
    dst[(size_t)(c0 + ty + i) * R + r0 + tx] = (f16)tile[tx][ty + i];
}

// ---------------------------------------------------------------------------
// C = A[M,K] * Bt[N,K]^T + bias ; 128x128 tile, BK=32, 4 waves (2x2 of 64x64)
template <bool OUT16>
__global__ __launch_bounds__(256) void gemm_f16(
    const f16* __restrict__ A, const f16* __restrict__ Bt,
    const float* __restrict__ bias, void* __restrict__ Cout, int M, int N,
    int K) {
  __shared__ __align__(16) f16 sA[128 * 32];
  __shared__ __align__(16) f16 sB[128 * 32];
  const int tid = threadIdx.x;
  const int wave = tid >> 6, lane = tid & 63;
  const int quad = lane >> 4, l16 = lane & 15;
  const int m0 = blockIdx.y * 128, n0 = blockIdx.x * 128;
  const int wm = (wave >> 1) * 64, wn = (wave & 1) * 64;
  const int rowA = lane >> 2, chunkA = lane & 3;

  f32x4 acc[4][4] = {};

  for (int k0 = 0; k0 < K; k0 += 32) {
#pragma unroll
    for (int i = 0; i < 2; i++) {
      int r = wave * 2 + i;
      const f16* ga = A + (size_t)(m0 + r * 16 + rowA) * K + k0 + chunkA * 8;
      ASYNC_COPY16(ga, &sA[r * 512]);
      const f16* gb = Bt + (size_t)(n0 + r * 16 + rowA) * K + k0 + chunkA * 8;
      ASYNC_COPY16(gb, &sB[r * 512]);
    }
    __syncthreads();

    half8 af[4], bf[4];
#pragma unroll
    for (int i = 0; i < 4; i++) {
      af[i] = *(const half8*)&sA[(wm + i * 16 + l16) * 32 + quad * 8];
      bf[i] = *(const half8*)&sB[(wn + i * 16 + l16) * 32 + quad * 8];
    }
#pragma unroll
    for (int i = 0; i < 4; i++)
#pragma unroll
      for (int j = 0; j < 4; j++)
        acc[i][j] = __builtin_amdgcn_mfma_f32_16x16x32_f16(af[i], bf[j],
                                                           acc[i][j], 0, 0, 0);
    __syncthreads();
  }

#pragma unroll
  for (int i = 0; i < 4; i++) {
    int row = m0 + wm + i * 16 + quad * 4;
#pragma unroll
    for (int j = 0; j < 4; j++) {
      int col = n0 + wn + j * 16 + l16;
      float bv = bias[col];
#pragma unroll
      for (int r = 0; r < 4; r++) {
        float v = acc[i][j][r] + bv;
        if (OUT16)
          ((f16*)Cout)[(size_t)(row + r) * N + col] = (f16)v;
        else
          ((float*)Cout)[(size_t)(row + r) * N + col] = v;
      }
    }
  }
}

// ---------------------------------------------------------------------------
// Split-K causal flash attention. 1D grid of 1280 blocks = 16 heads x 80
// (qt,chunk) pairs; each block does <=8 k-tiles. Single-chunk q-tiles
// (qt<=7) write final output; others write unnormalized partials + (m,l).
// All LDS tiles padded to 72-element rows -> conflict-free b128 access.
#define LROW 72
__global__ __launch_bounds__(256) void attn_split(
    const f16* __restrict__ qkv, f16* __restrict__ out,
    f16* __restrict__ Opart, float* __restrict__ ml) {
  const int b = blockIdx.x;
  const int h = b / 80;
  const int rr_ = b % 80;
  int qt, c, nc;
  if (rr_ < 8)       { qt = rr_;                c = 0;            nc = 1; }
  else if (rr_ < 24) { qt = 8 + ((rr_ - 8) >> 1);  c = (rr_ - 8) & 1;  nc = 2; }
  else if (rr_ < 48) { qt = 16 + (rr_ - 24) / 3;   c = (rr_ - 24) % 3; nc = 3; }
  else               { qt = 24 + ((rr_ - 48) >> 2); c = (rr_ - 48) & 3; nc = 4; }
  const int q0 = qt * 64;
  const int kt0 = c * 8;
  const int kt1 = (kt0 + 8 < qt + 1) ? kt0 + 8 : qt + 1;

  __shared__ __align__(16) f16 sK[64 * LROW];   // [s_k][d], padded
  __shared__ __align__(16) f16 sVt[64 * LROW];  // [d][s_k], padded
  __shared__ __align__(16) f16 sP[4][16 * LROW];

  const int tid = threadIdx.x;
  const int wave = tid >> 6, lane = tid & 63;
  const int quad = lane >> 4, l16 = lane & 15;

  // Q A-fragments, pre-scaled by sm_scale*log2(e) (softmax in exp2 domain)
  const f16* qbase =
      qkv + (size_t)(q0 + wave * 16 + l16) * 3072 + h * HDIM + quad * 8;
  half8 qf0 = *(const half8*)qbase;
  half8 qf1 = *(const half8*)(qbase + 32);
  const f16 qs = (f16)0.18033688f;  // 0.125 * log2(e)
#pragma unroll
  for (int j = 0; j < 8; j++) { qf0[j] *= qs; qf1[j] *= qs; }

  const f16* kbase = qkv + HID + h * HDIM;
  const f16* vbase = qkv + 2 * HID + h * HDIM;

  f32x4 o[4] = {};
  float m_i[4], l_i[4];
#pragma unroll
  for (int r = 0; r < 4; r++) { m_i[r] = -1e30f; l_i[r] = 0.f; }

  for (int kt = kt0; kt < kt1; kt++) {
    const int k0 = kt * 64;
    // K tile: coalesced half8 loads -> padded b128 LDS writes (conflict-free)
#pragma unroll
    for (int u = tid; u < 512; u += 256) {
      int s = u >> 3, cc = u & 7;
      *(half8*)&sK[s * LROW + cc * 8] =
          *(const half8*)(kbase + (size_t)(k0 + s) * 3072 + cc * 8);
    }
    // V^T: register transpose (coalesced scalar row reads, b128 writes)
#pragma unroll
    for (int u = tid; u < 512; u += 256) {
      int d = u & 63, g = u >> 6;  // s0 = g*8
      half8 col;
#pragma unroll
      for (int j = 0; j < 8; j++)
        col[j] = vbase[(size_t)(k0 + g * 8 + j) * 3072 + d];
      *(half8*)&sVt[d * LROW + g * 8] = col;
    }
    __syncthreads();

    // S = Q K^T (exp2 domain)
    f32x4 sacc[4] = {};
#pragma unroll
    for (int n = 0; n < 4; n++) {
      half8 kf0 = *(const half8*)&sK[(n * 16 + l16) * LROW + quad * 8];
      half8 kf1 = *(const half8*)&sK[(n * 16 + l16) * LROW + 32 + quad * 8];
      sacc[n] = __builtin_amdgcn_mfma_f32_16x16x32_f16(qf0, kf0, sacc[n], 0, 0, 0);
      sacc[n] = __builtin_amdgcn_mfma_f32_16x16x32_f16(qf1, kf1, sacc[n], 0, 0, 0);
    }
    // causal mask only on the diagonal tile
    if (kt == qt) {
      const int rowg_base = q0 + wave * 16 + quad * 4;
#pragma unroll
      for (int n = 0; n < 4; n++) {
        int colg = k0 + n * 16 + l16;
#pragma unroll
        for (int r = 0; r < 4; r++)
          if (colg > rowg_base + r) sacc[n][r] = -1e30f;
      }
    }
    // online softmax (exp2 domain), reduce across 16 lanes of each quad
#pragma unroll
    for (int r = 0; r < 4; r++) {
      float mx = fmaxf(fmaxf(sacc[0][r], sacc[1][r]),
                       fmaxf(sacc[2][r], sacc[3][r]));
#pragma unroll
      for (int off = 1; off < 16; off <<= 1) mx = fmaxf(mx, __shfl_xor(mx, off));
      float mnew = fmaxf(m_i[r], mx);
      float alpha = exp2f(m_i[r] - mnew);
      float rs = 0.f;
#pragma unroll
      for (int n = 0; n < 4; n++) {
        float p = exp2f(sacc[n][r] - mnew);
        sacc[n][r] = p;
        rs += p;
      }
#pragma unroll
      for (int off = 1; off < 16; off <<= 1) rs += __shfl_xor(rs, off);
      l_i[r] = l_i[r] * alpha + rs;
      m_i[r] = mnew;
#pragma unroll
      for (int j = 0; j < 4; j++) o[j][r] *= alpha;
    }
    // P: C-layout -> LDS (wave-private, padded) -> A-layout
#pragma unroll
    for (int n = 0; n < 4; n++)
#pragma unroll
      for (int r = 0; r < 4; r++)
        sP[wave][(quad * 4 + r) * LROW + n * 16 + l16] = (f16)sacc[n][r];
    half8 pf0 = *(const half8*)&sP[wave][l16 * LROW + quad * 8];
    half8 pf1 = *(const half8*)&sP[wave][l16 * LROW + 32 + quad * 8];
    // O += P V
#pragma unroll
    for (int j = 0; j < 4; j++) {
      half8 vf0 = *(const half8*)&sVt[(j * 16 + l16) * LROW + quad * 8];
      half8 vf1 = *(const half8*)&sVt[(j * 16 + l16) * LROW + 32 + quad * 8];
      o[j] = __builtin_amdgcn_mfma_f32_16x16x32_f16(pf0, vf0, o[j], 0, 0, 0);
      o[j] = __builtin_amdgcn_mfma_f32_16x16x32_f16(pf1, vf1, o[j], 0, 0, 0);
    }
    __syncthreads();
  }

  if (nc == 1) {
    // single chunk: write normalized output directly
#pragma unroll
    for (int j = 0; j < 4; j++) {
      int col = h * HDIM + j * 16 + l16;
#pragma unroll
      for (int r = 0; r < 4; r++) {
        int row = q0 + wave * 16 + quad * 4 + r;
        out[(size_t)row * HID + col] = (f16)(o[j][r] / l_i[r]);
      }
    }
  } else {
    // slot index: per-head 72 slots (qt 8..15: 2, 16..23: 3, 24..31: 4)
    int base;
    if (qt < 16)      base = (qt - 8) * 2 + c;
    else if (qt < 24) base = 16 + (qt - 16) * 3 + c;
    else              base = 40 + (qt - 24) * 4 + c;
    const int slot = h * 72 + base;
    f16* op = Opart + (size_t)slot * 4096;
#pragma unroll
    for (int j = 0; j < 4; j++)
#pragma unroll
      for (int r = 0; r < 4; r++)
        op[(wave * 16 + quad * 4 + r) * 64 + j * 16 + l16] = (f16)o[j][r];
    if (l16 == 0) {
#pragma unroll
      for (int r = 0; r < 4; r++) {
        int row = wave * 16 + quad * 4 + r;
        ml[slot * 128 + row] = m_i[r];
        ml[slot * 128 + 64 + row] = l_i[r];
      }
    }
  }
}

// ---------------------------------------------------------------------------
// Combine partials for qt >= 8. One thread per (head, qt, row, d).
__global__ __launch_bounds__(256) void attn_combine(
    const f16* __restrict__ Opart, const float* __restrict__ ml,
    f16* __restrict__ out) {
  int idx = blockIdx.x * 256 + threadIdx.x;
  int d = idx & 63;
  int r64 = (idx >> 6) & 63;
  int rest = idx >> 12;  // 0..383
  int qtl = rest % 24;
  int h = rest / 24;
  int qt = 8 + qtl;
  int g = qtl >> 3, i = qtl & 7;
  int nc = g + 2;
  int base = (g == 0) ? i * 2 : (g == 1) ? 16 + i * 3 : 40 + i * 4;
  int slot0 = h * 72 + base;

  float m[4], l[4];
  float M = -1e30f;
  for (int cc = 0; cc < nc; cc++) {
    m[cc] = ml[(slot0 + cc) * 128 + r64];
    l[cc] = ml[(slot0 + cc) * 128 + 64 + r64];
    M = fmaxf(M, m[cc]);
  }
  float L = 0.f, acc = 0.f;
  for (int cc = 0; cc < nc; cc++) {
    float w = exp2f(m[cc] - M);
    L += w * l[cc];
    acc += w * (float)Opart[(size_t)(slot0 + cc) * 4096 + r64 * 64 + d];
  }
  out[(size_t)(qt * 64 + r64) * HID + h * HDIM + d] = (f16)(acc / L);
}

// ---------------------------------------------------------------------------
extern "C" void kernel_launch(void* const* d_in, const int* in_sizes, int n_in,
                              void* d_out, int out_size, void* d_ws,
                              size_t ws_size, hipStream_t stream) {
  const float* h = (const float*)d_in[0];    // [2048,1024]
  const float* wa = (const float*)d_in[1];   // [1024,3072]
  const float* ba = (const float*)d_in[2];   // [3072]
  const float* wp = (const float*)d_in[3];   // [1024,1024]
  const float* bp = (const float*)d_in[4];   // [1024]
  float* out = (float*)d_out;                // [2048,1024] fp32

  char* ws = (char*)d_ws;
  f16* h16 = (f16*)(ws);                       //  4 MiB (dead after GEMM1)
  f16* waT = (f16*)(ws + (4u << 20));          //  6 MiB (dead after GEMM1)
  f16* wpT = (f16*)(ws + (10u << 20));         //  2 MiB
  f16* qkv = (f16*)(ws + (12u << 20));         // 12 MiB
  f16* attn = (f16*)(ws + (24u << 20));        //  4 MiB
  // attention partials reuse the first 10 MiB after GEMM1:
  f16* Opart = (f16*)(ws);                     // 1152*4096*2 = 9,437,184 B
  float* mlbuf = (float*)(ws + 9437184);       // 1152*128*4  =   589,824 B

  cast_f32_f16<<<2048, 256, 0, stream>>>(h, h16, SEQ * HID);
  transpose_cast<<<dim3(96, 32), dim3(32, 8), 0, stream>>>(wa, waT, 1024, 3072);
  transpose_cast<<<dim3(32, 32), dim3(32, 8), 0, stream>>>(wp, wpT, 1024, 1024);
  // QKV = H @ Wattn + b  -> f16
  gemm_f16<true><<<dim3(24, 16), 256, 0, stream>>>(h16, waT, ba, qkv, SEQ,
                                                   3 * HID, HID);
  // split-K causal attention + combine
  attn_split<<<1280, 256, 0, stream>>>(qkv, attn, Opart, mlbuf);
  attn_combine<<<6144, 256, 0, stream>>>(Opart, mlbuf, attn);
  // OUT = attn @ Wproj + b -> fp32
  gemm_f16<false><<<dim3(8, 16), 256, 0, stream>>>(attn, wpT, bp, out, SEQ,
                                                   HID, HID);
}

// Round 3
// 166.722 us; speedup vs baseline: 1.4436x; 1.1958x over previous
//
#include <hip/hip_runtime.h>
#include <cstdint>
#include <cstddef>

// Problem constants
#define SEQ 2048
#define HID 1024
#define NHEAD 16
#define HDIM 64

typedef _Float16 f16;
typedef f16 half8 __attribute__((ext_vector_type(8)));
typedef f16 half4 __attribute__((ext_vector_type(4)));
typedef f16 half2_ __attribute__((ext_vector_type(2)));
typedef float f32x4 __attribute__((ext_vector_type(4)));

// async global->LDS, 16B per lane (wave-uniform LDS base + lane*16)
#define ASYNC_COPY16(g, l)                                                    \
  __builtin_amdgcn_global_load_lds(                                           \
      (const __attribute__((address_space(1))) void*)(const void*)(g),        \
      (__attribute__((address_space(3))) void*)(void*)(l), 16, 0, 0)

// ---------------------------------------------------------------------------
// fp32 -> f16 cast (4 elements / thread)
__global__ void cast_f32_f16(const float* __restrict__ src,
                             f16* __restrict__ dst, int n) {
  int i = (blockIdx.x * blockDim.x + threadIdx.x) * 4;
  if (i < n) {
    float4 v = *(const float4*)(src + i);
    half4 h;
    h[0] = (f16)v.x; h[1] = (f16)v.y; h[2] = (f16)v.z; h[3] = (f16)v.w;
    *(half4*)(dst + i) = h;
  }
}

// ---------------------------------------------------------------------------
// src[R][C] fp32 -> dst[C][R] f16 (LDS-tiled transpose)
__global__ void transpose_cast(const float* __restrict__ src,
                               f16* __restrict__ dst, int R, int C) {
  __shared__ float tile[32][33];
  int c0 = blockIdx.x * 32, r0 = blockIdx.y * 32;
  int tx = threadIdx.x, ty = threadIdx.y;  // 32 x 8
#pragma unroll
  for (int i = 0; i < 32; i += 8)
    tile[ty + i][tx] = src[(size_t)(r0 + ty + i) * C + c0 + tx];
  __syncthreads();
#pragma unroll
  for (int i = 0; i < 32; i += 8)
    dst[(size_t)(c0 + ty + i) * R + r0 + tx] = (f16)tile[tx][ty + i];
}

// ---------------------------------------------------------------------------
// C = A[M,K] * Bt[N,K]^T + bias ; BM x BN tile, BK=32, 4 waves as 2x2.
// Wave computes (BM/2) x (BN/2); FM=BM/32, FN=BN/32 fragments.
template <int BM, int BN, bool OUT16>
__global__ __launch_bounds__(256) void gemm_f16(
    const f16* __restrict__ A, const f16* __restrict__ Bt,
    const float* __restrict__ bias, void* __restrict__ Cout, int M, int N,
    int K) {
  constexpr int FM = BM / 32, FN = BN / 32;
  __shared__ __align__(16) f16 sA[BM * 32];
  __shared__ __align__(16) f16 sB[BN * 32];
  const int tid = threadIdx.x;
  const int wave = tid >> 6, lane = tid & 63;
  const int quad = lane >> 4, l16 = lane & 15;
  const int m0 = blockIdx.y * BM, n0 = blockIdx.x * BN;
  const int wm = (wave >> 1) * (BM / 2), wn = (wave & 1) * (BN / 2);
  const int rowA = lane >> 2, chunkA = lane & 3;

  f32x4 acc[FM][FN] = {};

  for (int k0 = 0; k0 < K; k0 += 32) {
#pragma unroll
    for (int r = wave; r < BM / 16; r += 4)
      ASYNC_COPY16(A + (size_t)(m0 + r * 16 + rowA) * K + k0 + chunkA * 8,
                   &sA[r * 512]);
#pragma unroll
    for (int r = wave; r < BN / 16; r += 4)
      ASYNC_COPY16(Bt + (size_t)(n0 + r * 16 + rowA) * K + k0 + chunkA * 8,
                   &sB[r * 512]);
    __syncthreads();

    half8 af[FM], bf[FN];
#pragma unroll
    for (int i = 0; i < FM; i++)
      af[i] = *(const half8*)&sA[(wm + i * 16 + l16) * 32 + quad * 8];
#pragma unroll
    for (int j = 0; j < FN; j++)
      bf[j] = *(const half8*)&sB[(wn + j * 16 + l16) * 32 + quad * 8];
#pragma unroll
    for (int i = 0; i < FM; i++)
#pragma unroll
      for (int j = 0; j < FN; j++)
        acc[i][j] = __builtin_amdgcn_mfma_f32_16x16x32_f16(af[i], bf[j],
                                                           acc[i][j], 0, 0, 0);
    __syncthreads();
  }

#pragma unroll
  for (int i = 0; i < FM; i++) {
    int row = m0 + wm + i * 16 + quad * 4;
#pragma unroll
    for (int j = 0; j < FN; j++) {
      int col = n0 + wn + j * 16 + l16;
      float bv = bias[col];
#pragma unroll
      for (int r = 0; r < 4; r++) {
        float v = acc[i][j][r] + bv;
        if (OUT16)
          ((f16*)Cout)[(size_t)(row + r) * N + col] = (f16)v;
        else
          ((float*)Cout)[(size_t)(row + r) * N + col] = v;
      }
    }
  }
}

// ---------------------------------------------------------------------------
// Split-K causal flash attention, TRANSPOSED-S formulation.
// S^T = K Q^T so each lane owns one q-column: softmax = in-lane reduce +
// 2 shuffles; m/l per-lane scalars. O^T = V^T P^T. Register-prefetch
// double-buffer on K/V global loads. 1280 blocks = 16 heads x 80 chunks.
#define LROW 72
#define KROW 72
__global__ __launch_bounds__(256) void attn_split(
    const f16* __restrict__ qkv, f16* __restrict__ out,
    f16* __restrict__ Opart, float* __restrict__ ml) {
  const int b = blockIdx.x;
  const int h = b / 80;
  const int rr_ = b % 80;
  int qt, c, nc;
  if (rr_ < 8)       { qt = rr_;                   c = 0;              nc = 1; }
  else if (rr_ < 24) { qt = 8 + ((rr_ - 8) >> 1);  c = (rr_ - 8) & 1;  nc = 2; }
  else if (rr_ < 48) { qt = 16 + (rr_ - 24) / 3;   c = (rr_ - 24) % 3; nc = 3; }
  else               { qt = 24 + ((rr_ - 48) >> 2); c = (rr_ - 48) & 3; nc = 4; }
  const int q0 = qt * 64;
  const int kt0 = c * 8;
  const int kt1 = (kt0 + 8 < qt + 1) ? kt0 + 8 : qt + 1;

  __shared__ __align__(16) f16 sK[64 * LROW];    // [s_k][d]
  __shared__ __align__(16) f16 sVt[64 * LROW];   // [d][s_k]
  __shared__ __align__(16) f16 sP[4][16 * KROW]; // per-wave P[q][k]

  const int tid = threadIdx.x;
  const int wave = tid >> 6, lane = tid & 63;
  const int quad = lane >> 4, l16 = lane & 15;

  // Q fragments (used as MFMA B operand), pre-scaled by sm_scale*log2(e)
  const f16* qbase =
      qkv + (size_t)(q0 + wave * 16 + l16) * 3072 + h * HDIM + quad * 8;
  half8 qf0 = *(const half8*)qbase;
  half8 qf1 = *(const half8*)(qbase + 32);
  const f16 qs = (f16)0.18033688f;  // 0.125 * log2(e)
#pragma unroll
  for (int j = 0; j < 8; j++) { qf0[j] *= qs; qf1[j] *= qs; }

  const f16* kbase = qkv + HID + h * HDIM;
  const f16* vbase = qkv + 2 * HID + h * HDIM;

  // staging coords
  const int ks_row = tid >> 3, ks_cc = tid & 7;  // K: 2 x (32 rows x 8 chunks)
  const int vs_d = tid & 63, vs_g = tid >> 6;    // V: 2 x (8 col-groups x 64 d)

  f32x4 o[4] = {};
  float m_i = -1e30f, l_i = 0.f;
  half8 kreg[2], vreg[2];

  // prefetch tile kt into registers
  auto prefetch = [&](int kt) {
    const int k0 = kt * 64;
#pragma unroll
    for (int i = 0; i < 2; i++) {
      kreg[i] = *(const half8*)(kbase + (size_t)(k0 + ks_row + i * 32) * 3072 +
                                ks_cc * 8);
      half8 col;
#pragma unroll
      for (int j = 0; j < 8; j++)
        col[j] = vbase[(size_t)(k0 + (vs_g + i * 4) * 8 + j) * 3072 + vs_d];
      vreg[i] = col;
    }
  };

  prefetch(kt0);
  for (int kt = kt0; kt < kt1; kt++) {
    const int k0 = kt * 64;
    // commit staged registers to LDS
#pragma unroll
    for (int i = 0; i < 2; i++) {
      *(half8*)&sK[(ks_row + i * 32) * LROW + ks_cc * 8] = kreg[i];
      *(half8*)&sVt[vs_d * LROW + (vs_g + i * 4) * 8] = vreg[i];
    }
    __syncthreads();
    if (kt + 1 < kt1) prefetch(kt + 1);  // in flight during compute

    // S^T = K Q^T : D row = k-local, col = q-local (= l16)
    f32x4 sacc[4] = {};
#pragma unroll
    for (int kb = 0; kb < 4; kb++) {
      half8 kf0 = *(const half8*)&sK[(kb * 16 + l16) * LROW + quad * 8];
      half8 kf1 = *(const half8*)&sK[(kb * 16 + l16) * LROW + 32 + quad * 8];
      sacc[kb] =
          __builtin_amdgcn_mfma_f32_16x16x32_f16(kf0, qf0, sacc[kb], 0, 0, 0);
      sacc[kb] =
          __builtin_amdgcn_mfma_f32_16x16x32_f16(kf1, qf1, sacc[kb], 0, 0, 0);
    }
    // causal mask, diagonal tile only: k_g > q_g
    if (kt == qt) {
      const int qg = q0 + wave * 16 + l16;
#pragma unroll
      for (int kb = 0; kb < 4; kb++) {
        int kg = k0 + kb * 16 + quad * 4;
#pragma unroll
        for (int r = 0; r < 4; r++)
          if (kg + r > qg) sacc[kb][r] = -1e30f;
      }
    }
    // online softmax: lane owns q = l16 fully (16 values) + quad butterfly
    float mx = -1e30f;
#pragma unroll
    for (int kb = 0; kb < 4; kb++)
#pragma unroll
      for (int r = 0; r < 4; r++) mx = fmaxf(mx, sacc[kb][r]);
    mx = fmaxf(mx, __shfl_xor(mx, 16));
    mx = fmaxf(mx, __shfl_xor(mx, 32));
    const float mnew = fmaxf(m_i, mx);
    const float alpha = exp2f(m_i - mnew);
    float rs = 0.f;
#pragma unroll
    for (int kb = 0; kb < 4; kb++)
#pragma unroll
      for (int r = 0; r < 4; r++) {
        float p = exp2f(sacc[kb][r] - mnew);
        sacc[kb][r] = p;
        rs += p;
      }
    rs += __shfl_xor(rs, 16);
    rs += __shfl_xor(rs, 32);
    l_i = l_i * alpha + rs;
    m_i = mnew;
#pragma unroll
    for (int j = 0; j < 4; j++)
#pragma unroll
      for (int r = 0; r < 4; r++) o[j][r] *= alpha;

    // P store: lane writes P[q=l16][k = kb*16+quad*4+r] as f16x2 pairs
    f16* pw = &sP[wave][l16 * KROW];
#pragma unroll
    for (int kb = 0; kb < 4; kb++)
#pragma unroll
      for (int rp = 0; rp < 2; rp++) {
        half2_ pv;
        pv[0] = (f16)sacc[kb][rp * 2];
        pv[1] = (f16)sacc[kb][rp * 2 + 1];
        *(half2_*)&pw[kb * 16 + quad * 4 + rp * 2] = pv;
      }
    // P^T B-frags: lane reads P[q=l16][k = ks*32 + quad*8 + j] (16B aligned)
    half8 pf0 = *(const half8*)&pw[quad * 8];
    half8 pf1 = *(const half8*)&pw[32 + quad * 8];
    // O^T += V^T P^T : D row = d-local, col = q-local
#pragma unroll
    for (int j = 0; j < 4; j++) {
      half8 vf0 = *(const half8*)&sVt[(j * 16 + l16) * LROW + quad * 8];
      half8 vf1 = *(const half8*)&sVt[(j * 16 + l16) * LROW + 32 + quad * 8];
      o[j] = __builtin_amdgcn_mfma_f32_16x16x32_f16(vf0, pf0, o[j], 0, 0, 0);
      o[j] = __builtin_amdgcn_mfma_f32_16x16x32_f16(vf1, pf1, o[j], 0, 0, 0);
    }
    __syncthreads();  // protect sK/sVt before next commit
  }

  if (nc == 1) {
    const float inv = 1.f / l_i;
    f16* orow = out + (size_t)(q0 + wave * 16 + l16) * HID + h * HDIM;
#pragma unroll
    for (int j = 0; j < 4; j++) {
      half4 hv;
#pragma unroll
      for (int r = 0; r < 4; r++) hv[r] = (f16)(o[j][r] * inv);
      *(half4*)&orow[j * 16 + quad * 4] = hv;
    }
  } else {
    int base;
    if (qt < 16)      base = (qt - 8) * 2 + c;
    else if (qt < 24) base = 16 + (qt - 16) * 3 + c;
    else              base = 40 + (qt - 24) * 4 + c;
    const int slot = h * 72 + base;
    f16* op = Opart + (size_t)slot * 4096 + (wave * 16 + l16) * 64;
#pragma unroll
    for (int j = 0; j < 4; j++) {
      half4 hv;
#pragma unroll
      for (int r = 0; r < 4; r++) hv[r] = (f16)o[j][r];
      *(half4*)&op[j * 16 + quad * 4] = hv;
    }
    if (quad == 0) {
      ml[slot * 128 + wave * 16 + l16] = m_i;
      ml[slot * 128 + 64 + wave * 16 + l16] = l_i;
    }
  }
}

// ---------------------------------------------------------------------------
// Combine partials for qt >= 8. One thread per (head, qt, row, d).
__global__ __launch_bounds__(256) void attn_combine(
    const f16* __restrict__ Opart, const float* __restrict__ ml,
    f16* __restrict__ out) {
  int idx = blockIdx.x * 256 + threadIdx.x;
  int d = idx & 63;
  int r64 = (idx >> 6) & 63;
  int rest = idx >> 12;  // 0..383
  int qtl = rest % 24;
  int h = rest / 24;
  int qt = 8 + qtl;
  int g = qtl >> 3, i = qtl & 7;
  int nc = g + 2;
  int base = (g == 0) ? i * 2 : (g == 1) ? 16 + i * 3 : 40 + i * 4;
  int slot0 = h * 72 + base;

  float m[4], l[4];
  float M = -1e30f;
  for (int cc = 0; cc < nc; cc++) {
    m[cc] = ml[(slot0 + cc) * 128 + r64];
    l[cc] = ml[(slot0 + cc) * 128 + 64 + r64];
    M = fmaxf(M, m[cc]);
  }
  float L = 0.f, acc = 0.f;
  for (int cc = 0; cc < nc; cc++) {
    float w = exp2f(m[cc] - M);
    L += w * l[cc];
    acc += w * (float)Opart[(size_t)(slot0 + cc) * 4096 + r64 * 64 + d];
  }
  out[(size_t)(qt * 64 + r64) * HID + h * HDIM + d] = (f16)(acc / L);
}

// ---------------------------------------------------------------------------
extern "C" void kernel_launch(void* const* d_in, const int* in_sizes, int n_in,
                              void* d_out, int out_size, void* d_ws,
                              size_t ws_size, hipStream_t stream) {
  const float* h = (const float*)d_in[0];    // [2048,1024]
  const float* wa = (const float*)d_in[1];   // [1024,3072]
  const float* ba = (const float*)d_in[2];   // [3072]
  const float* wp = (const float*)d_in[3];   // [1024,1024]
  const float* bp = (const float*)d_in[4];   // [1024]
  float* out = (float*)d_out;                // [2048,1024] fp32

  char* ws = (char*)d_ws;
  f16* h16 = (f16*)(ws);                       //  4 MiB (dead after GEMM1)
  f16* waT = (f16*)(ws + (4u << 20));          //  6 MiB (dead after GEMM1)
  f16* wpT = (f16*)(ws + (10u << 20));         //  2 MiB
  f16* qkv = (f16*)(ws + (12u << 20));         // 12 MiB
  f16* attn = (f16*)(ws + (24u << 20));        //  4 MiB
  f16* Opart = (f16*)(ws);                     // reuse: 1152*4096*2 B
  float* mlbuf = (float*)(ws + 9437184);       // 1152*128*4 B

  cast_f32_f16<<<2048, 256, 0, stream>>>(h, h16, SEQ * HID);
  transpose_cast<<<dim3(96, 32), dim3(32, 8), 0, stream>>>(wa, waT, 1024, 3072);
  transpose_cast<<<dim3(32, 32), dim3(32, 8), 0, stream>>>(wp, wpT, 1024, 1024);
  // QKV = H @ Wattn + b -> f16 ; 128x64 tiles, 768 blocks (3/CU)
  gemm_f16<128, 64, true><<<dim3(48, 16), 256, 0, stream>>>(
      h16, waT, ba, qkv, SEQ, 3 * HID, HID);
  // split-K causal attention + combine
  attn_split<<<1280, 256, 0, stream>>>(qkv, attn, Opart, mlbuf);
  attn_combine<<<6144, 256, 0, stream>>>(Opart, mlbuf, attn);
  // OUT = attn @ Wproj + b -> fp32 ; 64x64 tiles, 512 blocks (2/CU)
  gemm_f16<64, 64, false><<<dim3(16, 32), 256, 0, stream>>>(
      attn, wpT, bp, out, SEQ, HID, HID);
}

// Round 4
// 160.518 us; speedup vs baseline: 1.4994x; 1.0386x over previous
//
#include <hip/hip_runtime.h>
#include <cstdint>
#include <cstddef>

// Problem constants
#define SEQ 2048
#define HID 1024
#define NHEAD 16
#define HDIM 64

typedef _Float16 f16;
typedef f16 half8 __attribute__((ext_vector_type(8)));
typedef f16 half4 __attribute__((ext_vector_type(4)));
typedef f16 half2_ __attribute__((ext_vector_type(2)));
typedef float f32x4 __attribute__((ext_vector_type(4)));

// async global->LDS, 16B per lane (wave-uniform LDS base + lane*16)
#define ASYNC_COPY16(g, l)                                                    \
  __builtin_amdgcn_global_load_lds(                                           \
      (const __attribute__((address_space(1))) void*)(const void*)(g),        \
      (__attribute__((address_space(3))) void*)(void*)(l), 16, 0, 0)

// ---------------------------------------------------------------------------
// Merged prologue: blocks [0,3072) transpose-cast w_attn, [3072,4096)
// transpose-cast w_proj, [4096,6144) cast hidden fp32->f16.
__global__ __launch_bounds__(256) void prologue(
    const float* __restrict__ h, const float* __restrict__ wa,
    const float* __restrict__ wp, f16* __restrict__ h16,
    f16* __restrict__ waT, f16* __restrict__ wpT) {
  const int b = blockIdx.x, tid = threadIdx.x;
  if (b >= 4096) {  // cast h
    int i = ((b - 4096) * 256 + tid) * 4;
    float4 v = *(const float4*)(h + i);
    half4 o;
    o[0] = (f16)v.x; o[1] = (f16)v.y; o[2] = (f16)v.z; o[3] = (f16)v.w;
    *(half4*)(h16 + i) = o;
    return;
  }
  // transpose-cast src[R=1024][C] -> dst[C][1024]
  const float* src; f16* dst; int C, bx, by;
  if (b < 3072) { src = wa; dst = waT; C = 3072; bx = b % 96; by = b / 96; }
  else { int t = b - 3072; src = wp; dst = wpT; C = 1024; bx = t & 31; by = t >> 5; }
  __shared__ float tile[32][33];
  const int tx = tid & 31, ty = tid >> 5;  // 32 x 8
  const int c0 = bx * 32, r0 = by * 32;
#pragma unroll
  for (int i = 0; i < 32; i += 8)
    tile[ty + i][tx] = src[(size_t)(r0 + ty + i) * C + c0 + tx];
  __syncthreads();
#pragma unroll
  for (int i = 0; i < 32; i += 8)
    dst[(size_t)(c0 + ty + i) * 1024 + r0 + tx] = (f16)tile[tx][ty + i];
}

// ---------------------------------------------------------------------------
// C = A[M,K] * Bt[N,K]^T + bias ; BM x BN tile, BK=32, 4 waves as 2x2.
template <int BM, int BN, bool OUT16>
__global__ __launch_bounds__(256) void gemm_f16(
    const f16* __restrict__ A, const f16* __restrict__ Bt,
    const float* __restrict__ bias, void* __restrict__ Cout, int M, int N,
    int K) {
  constexpr int FM = BM / 32, FN = BN / 32;
  __shared__ __align__(16) f16 sA[BM * 32];
  __shared__ __align__(16) f16 sB[BN * 32];
  const int tid = threadIdx.x;
  const int wave = tid >> 6, lane = tid & 63;
  const int quad = lane >> 4, l16 = lane & 15;
  const int m0 = blockIdx.y * BM, n0 = blockIdx.x * BN;
  const int wm = (wave >> 1) * (BM / 2), wn = (wave & 1) * (BN / 2);
  const int rowA = lane >> 2, chunkA = lane & 3;

  f32x4 acc[FM][FN] = {};

  for (int k0 = 0; k0 < K; k0 += 32) {
#pragma unroll
    for (int r = wave; r < BM / 16; r += 4)
      ASYNC_COPY16(A + (size_t)(m0 + r * 16 + rowA) * K + k0 + chunkA * 8,
                   &sA[r * 512]);
#pragma unroll
    for (int r = wave; r < BN / 16; r += 4)
      ASYNC_COPY16(Bt + (size_t)(n0 + r * 16 + rowA) * K + k0 + chunkA * 8,
                   &sB[r * 512]);
    __syncthreads();

    half8 af[FM], bf[FN];
#pragma unroll
    for (int i = 0; i < FM; i++)
      af[i] = *(const half8*)&sA[(wm + i * 16 + l16) * 32 + quad * 8];
#pragma unroll
    for (int j = 0; j < FN; j++)
      bf[j] = *(const half8*)&sB[(wn + j * 16 + l16) * 32 + quad * 8];
#pragma unroll
    for (int i = 0; i < FM; i++)
#pragma unroll
      for (int j = 0; j < FN; j++)
        acc[i][j] = __builtin_amdgcn_mfma_f32_16x16x32_f16(af[i], bf[j],
                                                           acc[i][j], 0, 0, 0);
    __syncthreads();
  }

#pragma unroll
  for (int i = 0; i < FM; i++) {
    int row = m0 + wm + i * 16 + quad * 4;
#pragma unroll
    for (int j = 0; j < FN; j++) {
      int col = n0 + wn + j * 16 + l16;
      float bv = bias[col];
#pragma unroll
      for (int r = 0; r < 4; r++) {
        float v = acc[i][j][r] + bv;
        if (OUT16)
          ((f16*)Cout)[(size_t)(row + r) * N + col] = (f16)v;
        else
          ((float*)Cout)[(size_t)(row + r) * N + col] = v;
      }
    }
  }
}

// ---------------------------------------------------------------------------
// Split-K causal flash attention, transposed-S, 32 q-rows per wave (2 groups
// of 16 sharing all K/V fragment reads -> ~40% less LDS traffic / element).
// Block = 128 q-rows. Grid: 16 heads x 40 (m,chunk) pairs = 640 blocks.
#define LROW 72
__global__ __launch_bounds__(256, 3) void attn_split(
    const f16* __restrict__ qkv, f16* __restrict__ out,
    f16* __restrict__ Opart, float* __restrict__ ml) {
  const int b = blockIdx.x;
  const int h = b / 40;
  const int t = b % 40;
  int m, c, nc;
  if (t < 4)       { m = t;                 c = 0;      nc = 1; }
  else if (t < 12) { int u = t - 4;  m = 4 + (u >> 1);  c = u & 1; nc = 2; }
  else if (t < 24) { int u = t - 12; m = 8 + u / 3;     c = u % 3; nc = 3; }
  else             { int u = t - 24; m = 12 + (u >> 2); c = u & 3; nc = 4; }
  const int q0 = m * 128;
  const int T = 2 * m + 2;             // k64 tiles needed (causal)
  const int kt0 = c * 8;
  const int kt1 = (kt0 + 8 < T) ? kt0 + 8 : T;
  const int maskFrom = 2 * m;          // diagonal-overlap tiles

  __shared__ __align__(16) f16 sK[64 * LROW];      // [s_k][d]
  __shared__ __align__(16) f16 sVt[64 * LROW];     // [d][s_k]
  __shared__ __align__(16) f16 sP[4][32 * LROW];   // per-wave P[q][k]

  const int tid = threadIdx.x;
  const int wave = tid >> 6, lane = tid & 63;
  const int quad = lane >> 4, l16 = lane & 15;

  // Q fragments for both q-groups, pre-scaled by sm_scale*log2(e)
  const f16 qs = (f16)0.18033688f;  // 0.125 * log2(e)
  half8 qf[2][2];
#pragma unroll
  for (int g = 0; g < 2; g++) {
    const f16* qb = qkv + (size_t)(q0 + wave * 32 + g * 16 + l16) * 3072 +
                    h * HDIM + quad * 8;
    qf[g][0] = *(const half8*)qb;
    qf[g][1] = *(const half8*)(qb + 32);
#pragma unroll
    for (int j = 0; j < 8; j++) { qf[g][0][j] *= qs; qf[g][1][j] *= qs; }
  }

  const f16* kbase = qkv + HID + h * HDIM;
  const f16* vbase = qkv + 2 * HID + h * HDIM;
  const int ks_row = tid >> 3, ks_cc = tid & 7;
  const int vs_d = tid & 63, vs_g = tid >> 6;

  f32x4 o[2][4] = {};
  float m_i[2] = {-1e30f, -1e30f}, l_i[2] = {0.f, 0.f};
  half8 kreg[2], vreg[2];

  auto prefetch = [&](int kt) {
    const int k0 = kt * 64;
#pragma unroll
    for (int i = 0; i < 2; i++) {
      kreg[i] = *(const half8*)(kbase + (size_t)(k0 + ks_row + i * 32) * 3072 +
                                ks_cc * 8);
      half8 col;
#pragma unroll
      for (int j = 0; j < 8; j++)
        col[j] = vbase[(size_t)(k0 + (vs_g + i * 4) * 8 + j) * 3072 + vs_d];
      vreg[i] = col;
    }
  };

  prefetch(kt0);
  for (int kt = kt0; kt < kt1; kt++) {
    const int k0 = kt * 64;
#pragma unroll
    for (int i = 0; i < 2; i++) {
      *(half8*)&sK[(ks_row + i * 32) * LROW + ks_cc * 8] = kreg[i];
      *(half8*)&sVt[vs_d * LROW + (vs_g + i * 4) * 8] = vreg[i];
    }
    __syncthreads();
    if (kt + 1 < kt1) prefetch(kt + 1);

    // S^T = K Q^T ; K-frag reads shared across both q-groups
    f32x4 sacc[2][4] = {};
#pragma unroll
    for (int kb = 0; kb < 4; kb++) {
      half8 kf0 = *(const half8*)&sK[(kb * 16 + l16) * LROW + quad * 8];
      half8 kf1 = *(const half8*)&sK[(kb * 16 + l16) * LROW + 32 + quad * 8];
#pragma unroll
      for (int g = 0; g < 2; g++) {
        sacc[g][kb] = __builtin_amdgcn_mfma_f32_16x16x32_f16(kf0, qf[g][0],
                                                             sacc[g][kb], 0, 0, 0);
        sacc[g][kb] = __builtin_amdgcn_mfma_f32_16x16x32_f16(kf1, qf[g][1],
                                                             sacc[g][kb], 0, 0, 0);
      }
    }
    // causal mask on diagonal-overlap tiles
    if (kt >= maskFrom) {
#pragma unroll
      for (int g = 0; g < 2; g++) {
        const int qg = q0 + wave * 32 + g * 16 + l16;
#pragma unroll
        for (int kb = 0; kb < 4; kb++) {
          int kg = k0 + kb * 16 + quad * 4;
#pragma unroll
          for (int r = 0; r < 4; r++)
            if (kg + r > qg) sacc[g][kb][r] = -1e30f;
        }
      }
    }
    // online softmax per q-group (lane owns one q-column per group)
#pragma unroll
    for (int g = 0; g < 2; g++) {
      float mx = -1e30f;
#pragma unroll
      for (int kb = 0; kb < 4; kb++)
#pragma unroll
        for (int r = 0; r < 4; r++) mx = fmaxf(mx, sacc[g][kb][r]);
      mx = fmaxf(mx, __shfl_xor(mx, 16));
      mx = fmaxf(mx, __shfl_xor(mx, 32));
      const float mnew = fmaxf(m_i[g], mx);
      const float alpha = exp2f(m_i[g] - mnew);
      float rs = 0.f;
#pragma unroll
      for (int kb = 0; kb < 4; kb++)
#pragma unroll
        for (int r = 0; r < 4; r++) {
          float p = exp2f(sacc[g][kb][r] - mnew);
          sacc[g][kb][r] = p;
          rs += p;
        }
      rs += __shfl_xor(rs, 16);
      rs += __shfl_xor(rs, 32);
      l_i[g] = l_i[g] * alpha + rs;
      m_i[g] = mnew;
#pragma unroll
      for (int j = 0; j < 4; j++)
#pragma unroll
        for (int r = 0; r < 4; r++) o[g][j][r] *= alpha;
      // P store (wave-private LDS, in-order within wave)
      f16* pw = &sP[wave][(g * 16 + l16) * LROW];
#pragma unroll
      for (int kb = 0; kb < 4; kb++)
#pragma unroll
        for (int rp = 0; rp < 2; rp++) {
          half2_ pv;
          pv[0] = (f16)sacc[g][kb][rp * 2];
          pv[1] = (f16)sacc[g][kb][rp * 2 + 1];
          *(half2_*)&pw[kb * 16 + quad * 4 + rp * 2] = pv;
        }
    }
    // O^T += V^T P^T ; V-frag reads shared across both q-groups
#pragma unroll
    for (int j = 0; j < 4; j++) {
      half8 vf0 = *(const half8*)&sVt[(j * 16 + l16) * LROW + quad * 8];
      half8 vf1 = *(const half8*)&sVt[(j * 16 + l16) * LROW + 32 + quad * 8];
#pragma unroll
      for (int g = 0; g < 2; g++) {
        half8 pf0 = *(const half8*)&sP[wave][(g * 16 + l16) * LROW + quad * 8];
        half8 pf1 =
            *(const half8*)&sP[wave][(g * 16 + l16) * LROW + 32 + quad * 8];
        o[g][j] = __builtin_amdgcn_mfma_f32_16x16x32_f16(vf0, pf0, o[g][j], 0, 0, 0);
        o[g][j] = __builtin_amdgcn_mfma_f32_16x16x32_f16(vf1, pf1, o[g][j], 0, 0, 0);
      }
    }
    __syncthreads();
  }

  if (nc == 1) {
#pragma unroll
    for (int g = 0; g < 2; g++) {
      const float inv = 1.f / l_i[g];
      f16* orow =
          out + (size_t)(q0 + wave * 32 + g * 16 + l16) * HID + h * HDIM;
#pragma unroll
      for (int j = 0; j < 4; j++) {
        half4 hv;
#pragma unroll
        for (int r = 0; r < 4; r++) hv[r] = (f16)(o[g][j][r] * inv);
        *(half4*)&orow[j * 16 + quad * 4] = hv;
      }
    }
  } else {
    // per-head 36 slots: m4..7 ->(m-4)*2, m8..11 ->8+(m-8)*3, m12..15 ->20+(m-12)*4
    int base;
    if (m < 8)       base = (m - 4) * 2;
    else if (m < 12) base = 8 + (m - 8) * 3;
    else             base = 20 + (m - 12) * 4;
    const int slot = h * 36 + base + c;
#pragma unroll
    for (int g = 0; g < 2; g++) {
      const int qrow = wave * 32 + g * 16 + l16;
      f16* op = Opart + (size_t)slot * 8192 + qrow * 64;
#pragma unroll
      for (int j = 0; j < 4; j++) {
        half4 hv;
#pragma unroll
        for (int r = 0; r < 4; r++) hv[r] = (f16)o[g][j][r];
        *(half4*)&op[j * 16 + quad * 4] = hv;
      }
      if (quad == 0) {
        ml[slot * 256 + qrow] = m_i[g];
        ml[slot * 256 + 128 + qrow] = l_i[g];
      }
    }
  }
}

// ---------------------------------------------------------------------------
// Combine partials for m >= 4. One thread per (head, m, row, d).
__global__ __launch_bounds__(256) void attn_combine(
    const f16* __restrict__ Opart, const float* __restrict__ ml,
    f16* __restrict__ out) {
  int idx = blockIdx.x * 256 + threadIdx.x;
  int d = idx & 63;
  int row = (idx >> 6) & 127;
  int rest = idx >> 13;      // 0..191
  int mi = rest % 12;        // m-4
  int h = rest / 12;
  int m = 4 + mi;
  int nc = (mi < 4) ? 2 : (mi < 8) ? 3 : 4;
  int base = (mi < 4) ? mi * 2 : (mi < 8) ? 8 + (mi - 4) * 3 : 20 + (mi - 8) * 4;
  int slot0 = h * 36 + base;

  float mm[4], ll[4];
  float M = -1e30f;
  for (int cc = 0; cc < nc; cc++) {
    mm[cc] = ml[(slot0 + cc) * 256 + row];
    ll[cc] = ml[(slot0 + cc) * 256 + 128 + row];
    M = fmaxf(M, mm[cc]);
  }
  float L = 0.f, acc = 0.f;
  for (int cc = 0; cc < nc; cc++) {
    float w = exp2f(mm[cc] - M);
    L += w * ll[cc];
    acc += w * (float)Opart[(size_t)(slot0 + cc) * 8192 + row * 64 + d];
  }
  out[(size_t)(m * 128 + row) * HID + h * HDIM + d] = (f16)(acc / L);
}

// ---------------------------------------------------------------------------
extern "C" void kernel_launch(void* const* d_in, const int* in_sizes, int n_in,
                              void* d_out, int out_size, void* d_ws,
                              size_t ws_size, hipStream_t stream) {
  const float* h = (const float*)d_in[0];    // [2048,1024]
  const float* wa = (const float*)d_in[1];   // [1024,3072]
  const float* ba = (const float*)d_in[2];   // [3072]
  const float* wp = (const float*)d_in[3];   // [1024,1024]
  const float* bp = (const float*)d_in[4];   // [1024]
  float* out = (float*)d_out;                // [2048,1024] fp32

  char* ws = (char*)d_ws;
  f16* h16 = (f16*)(ws);                       //  4 MiB (dead after GEMM1)
  f16* waT = (f16*)(ws + (4u << 20));          //  6 MiB (dead after GEMM1)
  f16* wpT = (f16*)(ws + (10u << 20));         //  2 MiB
  f16* qkv = (f16*)(ws + (12u << 20));         // 12 MiB
  f16* attn = (f16*)(ws + (24u << 20));        //  4 MiB
  f16* Opart = (f16*)(ws);                     // reuse: 576*8192*2 = 9.44 MB
  float* mlbuf = (float*)(ws + 9437184);       // 576*256*4 = 590 KB

  prologue<<<6144, 256, 0, stream>>>(h, wa, wp, h16, waT, wpT);
  // QKV = H @ Wattn + b -> f16 ; 128x128 tiles, 384 blocks
  gemm_f16<128, 128, true><<<dim3(24, 16), 256, 0, stream>>>(
      h16, waT, ba, qkv, SEQ, 3 * HID, HID);
  // split-K causal attention (128 q-rows/block) + combine
  attn_split<<<640, 256, 0, stream>>>(qkv, attn, Opart, mlbuf);
  attn_combine<<<6144, 256, 0, stream>>>(Opart, mlbuf, attn);
  // OUT = attn @ Wproj + b -> fp32 ; 64x64 tiles, 512 blocks (2/CU)
  gemm_f16<64, 64, false><<<dim3(16, 32), 256, 0, stream>>>(
      attn, wpT, bp, out, SEQ, HID, HID);
}